// Round 8
// baseline (351.358 us; speedup 1.0000x reference)
//
#include <hip/hip_runtime.h>
#include <hip/hip_bf16.h>

// GNNEncoder: 3-layer GraphSAGE (mean agg), N=50000, E=800000.
// h' = act( mean_agg(x@Wl) + x@(Wr+Ws) + (bl+bs) )   (matmul-first by linearity)
// R17: L2-panelized gather. R11/R13/R16 all hit ~2.1-2.3 TB/s gather BW
//      (3 structures, same number) + FETCH ~92MB = 8 XCD x full 12.8MB Y table
//      -> L3-latency-bound scatter (MSHR x latency cap). Fix: store Y in
//      32-col panels (3.2MB = fits each XCD L2); gather pass-per-panel
//      (outermost loop), nontemporal srcs/Zprev streams. 1 line-tag/row.

#define LB __launch_bounds__

typedef __attribute__((ext_vector_type(8))) short short8;
typedef __attribute__((ext_vector_type(4))) float f32x4;

__device__ __forceinline__ unsigned short bf16_rne(float f) {
  unsigned u = __builtin_bit_cast(unsigned, f);
  unsigned r = u + 0x7fffu + ((u >> 16) & 1u);
  return (unsigned short)(r >> 16);
}
__device__ __forceinline__ float bf16_to_f(unsigned short us) {
  return __builtin_bit_cast(float, (unsigned)us << 16);
}
__device__ __forceinline__ float bits_to_f(unsigned u) {
  return __builtin_bit_cast(float, u);
}

// async global->LDS, 16B per lane; lds ptr must be wave-uniform (HW adds lane*16)
__device__ __forceinline__ void async16(const void* g, void* l) {
  __builtin_amdgcn_global_load_lds((const __attribute__((address_space(1))) unsigned*)g,
                                   (__attribute__((address_space(3))) unsigned*)l, 16, 0, 0);
}

// ---------------- CSR build: bucketed 2-pass sort ----------------
#define BCAP 8192
#define P1_CHUNK 4096

__device__ __forceinline__ void p1_body(int bid, const int* __restrict__ src,
                                        const int* __restrict__ dst, int* __restrict__ bcnt,
                                        int2* __restrict__ pairs, int E) {
  __shared__ int cnt[256];
  __shared__ int base[256];
  const int tid = threadIdx.x;
  cnt[tid] = 0;
  __syncthreads();
  const int e0 = bid * P1_CHUNK;
  int myb[16], myr[16], mys[16], myd[16];
#pragma unroll
  for (int i = 0; i < 16; ++i) {
    int e = e0 + i * 256 + tid;
    myb[i] = -1;
    if (e < E) {
      int s = src[e], d = dst[e];
      int b = d >> 8;
      myb[i] = b;
      mys[i] = s;
      myd[i] = d;
      myr[i] = atomicAdd(&cnt[b], 1);
    }
  }
  __syncthreads();
  base[tid] = (cnt[tid] > 0) ? atomicAdd(&bcnt[tid], cnt[tid]) : 0;
  __syncthreads();
#pragma unroll
  for (int i = 0; i < 16; ++i) {
    int b = myb[i];
    if (b >= 0) {
      int p = base[b] + myr[i];
      if (p < BCAP) pairs[(size_t)b * BCAP + p] = make_int2(mys[i], myd[i]);
    }
  }
}

// Fused: per-bucket hist + local scan + ONE atomicAdd region-claim + place.
__device__ __forceinline__ void p234_body(int b, const int2* __restrict__ pairs,
                                          const int* __restrict__ bcnt, int* __restrict__ gcounter,
                                          int* __restrict__ row_start, int* __restrict__ deg_arr,
                                          float* __restrict__ scale, int* __restrict__ srcs, int N) {
  __shared__ int h[256];
  __shared__ int sc[256];
  __shared__ int cur[256];
  __shared__ int shared_bb;
  const int tid = threadIdx.x;
  h[tid] = 0;
  __syncthreads();
  int m = bcnt[b];
  if (m > BCAP) m = BCAP;
  for (int i = tid; i < m; i += 256) {
    atomicAdd(&h[pairs[(size_t)b * BCAP + i].y & 255], 1);
  }
  __syncthreads();
  const int deg = h[tid];
  sc[tid] = deg;
  __syncthreads();
  for (int off = 1; off < 256; off <<= 1) {
    int add = (tid >= off) ? sc[tid - off] : 0;
    __syncthreads();
    sc[tid] += add;
    __syncthreads();
  }
  if (tid == 0) shared_bb = atomicAdd(gcounter, sc[255]);
  __syncthreads();
  const int abs_off = shared_bb + sc[tid] - deg;
  const int node = b * 256 + tid;
  if (node < N) {
    row_start[node] = abs_off;
    deg_arr[node] = deg;
    scale[node] = 1.0f / (float)(deg > 1 ? deg : 1);
  }
  cur[tid] = abs_off;
  __syncthreads();
  for (int i = tid; i < m; i += 256) {
    int2 pr = pairs[(size_t)b * BCAP + i];
    int p = atomicAdd(&cur[pr.y & 255], 1);
    srcs[p] = pr.x;
  }
}

// ---------------- weights -> fragment-ordered hi/lo bf16 + bias ----------------
__device__ __forceinline__ void wpack_body(int wb, const float* __restrict__ Wl0,
                                           const float* __restrict__ Wr0,
                                           const float* __restrict__ Ws0,
                                           const float* __restrict__ bl0,
                                           const float* __restrict__ bs0,
                                           const float* __restrict__ Wl1,
                                           const float* __restrict__ Wr1,
                                           const float* __restrict__ Ws1,
                                           const float* __restrict__ bl1,
                                           const float* __restrict__ bs1,
                                           const float* __restrict__ Wl2,
                                           const float* __restrict__ Wr2,
                                           const float* __restrict__ Ws2,
                                           const float* __restrict__ bl2,
                                           const float* __restrict__ bs2, ushort* __restrict__ Bh0,
                                           ushort* __restrict__ Bo0, float* __restrict__ bb0,
                                           ushort* __restrict__ Bh1, ushort* __restrict__ Bo1,
                                           float* __restrict__ bb1, ushort* __restrict__ Bh2,
                                           ushort* __restrict__ Bo2, float* __restrict__ bb2) {
  const int layer = wb >> 7;
  const int xb = wb & 127;
  const float *Wl, *Wr, *Ws, *bl, *bs;
  ushort *Bh, *Bo;
  float* bb;
  int M;
  if (layer == 0) {
    Wl = Wl0; Wr = Wr0; Ws = Ws0; bl = bl0; bs = bs0; Bh = Bh0; Bo = Bo0; bb = bb0; M = 256;
  } else if (layer == 1) {
    Wl = Wl1; Wr = Wr1; Ws = Ws1; bl = bl1; bs = bs1; Bh = Bh1; Bo = Bo1; bb = bb1; M = 256;
  } else {
    Wl = Wl2; Wr = Wr2; Ws = Ws2; bl = bl2; bs = bs2; Bh = Bh2; Bo = Bo2; bb = bb2; M = 128;
  }
  const int DO = M / 2;
  int idx = xb * 256 + (int)threadIdx.x;
  if (idx < 128 * M) {
    int k = idx / M, c = idx - k * M;
    float v = (c < DO) ? Wl[k * DO + c] : (Wr[k * DO + (c - DO)] + Ws[k * DO + (c - DO)]);
    unsigned short h = bf16_rne(v);
    unsigned short l = bf16_rne(v - bf16_to_f(h));
    int d = ((k >> 3) * M + c) * 8 + (k & 7);
    Bh[d] = h;
    Bo[d] = l;
  }
  if (idx < DO) bb[idx] = bl[idx] + bs[idx];
}

// ---------------- MFMA GEMM (A = fp32 in LDS, swizzled 16B granules) ----------------
__device__ __forceinline__ void split8v(f32x4 f0, f32x4 f1, short8& h, short8& l) {
  float f[8] = {f0[0], f0[1], f0[2], f0[3], f1[0], f1[1], f1[2], f1[3]};
#pragma unroll
  for (int j = 0; j < 8; ++j) {
    unsigned u = __builtin_bit_cast(unsigned, f[j]);
    h[j] = (short)(u >> 16);
    l[j] = (short)bf16_rne(f[j] - bits_to_f(u & 0xffff0000u));
  }
}

// LDS layout: row r (BROWS rows) x 512B; granule g of row holds global granule
// g ^ (r&15). Wave tile 32x64 (acc 2x4). Y output PANELIZED: panel p = c>>5,
// element at Yb[(p*n + row)*32 + (c&31)].
template <int M>
__device__ __forceinline__ void gemm_compute(int bx, const char* smem,
                                             const ushort* __restrict__ Bhi,
                                             const ushort* __restrict__ Blo,
                                             ushort* __restrict__ Yb, float* __restrict__ Z,
                                             int n) {
  constexpr int DO = M / 2;
  constexpr int NWC = (M >= 256) ? 4 : 2;
  constexpr int NWR = 4 / NWC;
  constexpr int BROWS = 32 * NWR;
  const int tid = threadIdx.x;
  const int w = tid >> 6, l = tid & 63;
  const int q = l >> 4, m16 = l & 15;
  const int rowBase = bx * BROWS + (w / NWC) * 32;
  const int colBase = (w % NWC) * 64;

  f32x4 acc[2][4] = {};
  const int rl0 = (w / NWC) * 32 + m16;

#pragma unroll
  for (int s = 0; s < 4; ++s) {
    short8 ah[2], al[2], bh[4], bo[4];
    const int kb = s * 4 + q;
#pragma unroll
    for (int i = 0; i < 2; ++i) {
      int rl = rl0 + i * 16;  // rl & 15 == m16
      int g0 = (2 * kb) ^ m16;
      int g1 = (2 * kb + 1) ^ m16;
      f32x4 fa = *(const f32x4*)(smem + (size_t)rl * 512 + g0 * 16);
      f32x4 fb = *(const f32x4*)(smem + (size_t)rl * 512 + g1 * 16);
      split8v(fa, fb, ah[i], al[i]);
    }
#pragma unroll
    for (int j = 0; j < 4; ++j) {
      size_t off = ((size_t)kb * M + colBase + j * 16 + m16) * 8;
      bh[j] = *(const short8*)(Bhi + off);
      bo[j] = *(const short8*)(Blo + off);
    }
#pragma unroll
    for (int i = 0; i < 2; ++i)
#pragma unroll
      for (int j = 0; j < 4; ++j) {
        acc[i][j] = __builtin_amdgcn_mfma_f32_16x16x32_bf16(ah[i], bh[j], acc[i][j], 0, 0, 0);
        acc[i][j] = __builtin_amdgcn_mfma_f32_16x16x32_bf16(ah[i], bo[j], acc[i][j], 0, 0, 0);
        acc[i][j] = __builtin_amdgcn_mfma_f32_16x16x32_bf16(al[i], bh[j], acc[i][j], 0, 0, 0);
      }
  }

#pragma unroll
  for (int i = 0; i < 2; ++i) {
    int rb = rowBase + i * 16 + q * 4;
#pragma unroll
    for (int j = 0; j < 4; ++j) {
      int c = colBase + j * 16 + m16;
      int p = (colBase + j * 16) >> 5;       // panel (c>>5), lane-uniform part
      int cc = (j & 1) * 16 + m16;           // c & 31 (colBase multiple of 64)
#pragma unroll
      for (int r = 0; r < 4; ++r) {
        int row = rb + r;
        if (row < n) {
          float v = acc[i][j][r];
          if (c < DO)
            Yb[((size_t)p * n + row) * 32 + cc] = bf16_rne(v);
          else
            Z[(size_t)row * DO + (c - DO)] = v;
        }
      }
    }
  }
}

// layer-0 GEMM: stage x (fp32) global->LDS with inverse-swizzled source, then compute
__device__ __forceinline__ void gemm0_body(int bx, const float* __restrict__ x,
                                           const ushort* __restrict__ Bh,
                                           const ushort* __restrict__ Bo, ushort* __restrict__ Yb,
                                           float* __restrict__ Z, int n, char* smem) {
  const int tid = threadIdx.x;
  const int wbase = tid & ~63;
#pragma unroll
  for (int r = 0; r < 4; ++r) {  // 32 rows x 512B
    int ell = r * 256 + tid;
    int row = ell >> 5, gl = ell & 31;
    int grow = bx * 32 + row;
    if (grow >= n) grow = n - 1;
    int gs = gl ^ (row & 15);
    async16(x + (size_t)grow * 128 + gs * 4, smem + (size_t)(r * 256 + wbase) * 16);
  }
  __syncthreads();
  gemm_compute<256>(bx, smem, Bh, Bo, Yb, Z, n);
}

// ---------------- fused agg + next-layer GEMM (panelized gather) ----------------
// Pass loop over 4 panels outermost (XCD L2 keeps one 3.2MB panel hot).
// Quarter-per-node; lane li gathers 4B (cols 2li,2li+1 of panel) per row;
// 8-deep predicated bursts; nontemporal srcs/Zprev; lane-local epilogue;
// float2 write into swizzled LDS A-tile.
template <int M>
__global__ LB(256, 4) void fused_agg_gemm(const ushort* __restrict__ Y,
                                          const float* __restrict__ Zprev,
                                          const int* __restrict__ row_start,
                                          const int* __restrict__ deg_arr,
                                          const int* __restrict__ srcs,
                                          const float* __restrict__ scale,
                                          const float* __restrict__ bsum,
                                          const ushort* __restrict__ Bhi,
                                          const ushort* __restrict__ Blo, ushort* __restrict__ Yb,
                                          float* __restrict__ Zf, int n) {
  constexpr int BROWS = (M >= 256) ? 32 : 64;
  __shared__ __align__(16) char smem[BROWS * 512];
  const int tid = threadIdx.x;
  const int w = tid >> 6;
  const int lane = tid & 63;
  const int qt = lane >> 4;  // quarter -> node within wave's group of 4
  const int li = lane & 15;  // lane -> col pair within 32-col panel

#pragma unroll 1
  for (int p = 0; p < 4; ++p) {
    const ushort* Yp = Y + (size_t)p * n * 32;
#pragma unroll 1
    for (int t = 0; t < BROWS / 16; ++t) {
      const int r = t * 16 + w * 4 + qt;
      const int node = blockIdx.x * BROWS + r;
      const bool live = node < n;  // quarter-uniform
      const int cn = live ? node : n - 1;
      const int e0q = row_start[cn];
      const int cntq = live ? deg_arr[cn] : 0;
      const float sc = scale[cn];
      const int c0 = p * 32 + 2 * li;
      float zx = __builtin_nontemporal_load(Zprev + (size_t)cn * 128 + c0);
      float zy = __builtin_nontemporal_load(Zprev + (size_t)cn * 128 + c0 + 1);
      float bx = bsum[c0], by = bsum[c0 + 1];
      float a0 = 0.f, a1 = 0.f;

      int cm = cntq;  // wave-uniform trip count = max over quarters
      cm = max(cm, __shfl_xor(cm, 16));
      cm = max(cm, __shfl_xor(cm, 32));

      for (int base = 0; base < cm; base += 16) {
        int idx = (base + li < cntq) ? __builtin_nontemporal_load(srcs + e0q + base + li) : 0;
        int lim = cm - base;
        if (lim > 16) lim = 16;
        for (int jj = 0; jj < lim; jj += 8) {  // 8 rows in flight / quarter
          int s[8];
#pragma unroll
          for (int k = 0; k < 8; ++k) s[k] = __shfl(idx, (qt << 4) + jj + k);
          unsigned u[8];
#pragma unroll
          for (int k = 0; k < 8; ++k) {
            unsigned v = 0u;
            if (base + jj + k < cntq) v = *(const unsigned*)(Yp + (size_t)s[k] * 32 + li * 2);
            u[k] = v;
          }
#pragma unroll
          for (int k = 0; k < 8; ++k) {
            a0 += bits_to_f(u[k] << 16);
            a1 += bits_to_f(u[k] & 0xffff0000u);
          }
        }
      }
      float o0 = fmaxf(zx + sc * a0 + bx, 0.f);
      float o1 = fmaxf(zy + sc * a1 + by, 0.f);
      int b0 = p * 128 + li * 8;  // logical byte offset of col pair in row
      int sb = (((b0 >> 4) ^ (r & 15)) << 4) + (b0 & 15);
      *(float2*)(smem + (size_t)r * 512 + sb) = make_float2(o0, o1);
    }
  }
  __syncthreads();
  gemm_compute<M>(blockIdx.x, smem, Bhi, Blo, Yb, Zf, n);
}

// ---------------- fused launch-overlap kernels ----------------
__global__ LB(256) void fused_wpack_p1(const int* __restrict__ src, const int* __restrict__ dst,
                                       int* __restrict__ bcnt, int2* __restrict__ pairs, int E,
                                       int NP1, const float* Wl0, const float* Wr0, const float* Ws0,
                                       const float* bl0, const float* bs0, const float* Wl1,
                                       const float* Wr1, const float* Ws1, const float* bl1,
                                       const float* bs1, const float* Wl2, const float* Wr2,
                                       const float* Ws2, const float* bl2, const float* bs2,
                                       ushort* Bh0, ushort* Bo0, float* bb0, ushort* Bh1,
                                       ushort* Bo1, float* bb1, ushort* Bh2, ushort* Bo2,
                                       float* bb2) {
  if ((int)blockIdx.x < NP1) {
    p1_body(blockIdx.x, src, dst, bcnt, pairs, E);
  } else {
    wpack_body(blockIdx.x - NP1, Wl0, Wr0, Ws0, bl0, bs0, Wl1, Wr1, Ws1, bl1, bs1, Wl2, Wr2, Ws2,
               bl2, bs2, Bh0, Bo0, bb0, Bh1, Bo1, bb1, Bh2, Bo2, bb2);
  }
}

__global__ LB(256, 5) void fused_p234_gemm0(const int2* __restrict__ pairs,
                                            const int* __restrict__ bcnt, int* __restrict__ gcounter,
                                            int* __restrict__ row_start, int* __restrict__ deg_arr,
                                            float* __restrict__ scale, int* __restrict__ srcs, int N,
                                            const float* __restrict__ x,
                                            const ushort* __restrict__ Bh0,
                                            const ushort* __restrict__ Bo0, ushort* __restrict__ Yb,
                                            float* __restrict__ Zf, int NB) {
  __shared__ __align__(16) char smem[32 * 512];
  if ((int)blockIdx.x < NB) {
    p234_body(blockIdx.x, pairs, bcnt, gcounter, row_start, deg_arr, scale, srcs, N);
  } else {
    gemm0_body(blockIdx.x - NB, x, Bh0, Bo0, Yb, Zf, N, smem);
  }
}

// ---------------- final aggregation (DO=64, 2 panels) ----------------
__global__ LB(256, 4) void agg64_kernel(const ushort* __restrict__ Y, const float* __restrict__ Z,
                                        const int* __restrict__ row_start,
                                        const int* __restrict__ deg_arr, const int* __restrict__ srcs,
                                        const float* __restrict__ scale,
                                        const float* __restrict__ bsum, float* __restrict__ out,
                                        int n) {
  const int tid = threadIdx.x;
  const int lane = tid & 63;
  const int qt = lane >> 4;
  const int li = lane & 15;
  const int node = blockIdx.x * 16 + (tid >> 6) * 4 + qt;
  const bool live = node < n;  // quarter-uniform
  const int cn = live ? node : n - 1;
  const int e0q = row_start[cn];
  const int cntq = live ? deg_arr[cn] : 0;
  const float sc = scale[cn];

  int cm = cntq;
  cm = max(cm, __shfl_xor(cm, 16));
  cm = max(cm, __shfl_xor(cm, 32));

#pragma unroll 1
  for (int p = 0; p < 2; ++p) {
    const ushort* Yp = Y + (size_t)p * n * 32;
    const int c0 = p * 32 + 2 * li;
    float zx = __builtin_nontemporal_load(Z + (size_t)cn * 64 + c0);
    float zy = __builtin_nontemporal_load(Z + (size_t)cn * 64 + c0 + 1);
    float a0 = 0.f, a1 = 0.f;
    for (int base = 0; base < cm; base += 16) {
      int idx = (base + li < cntq) ? __builtin_nontemporal_load(srcs + e0q + base + li) : 0;
      int lim = cm - base;
      if (lim > 16) lim = 16;
      for (int jj = 0; jj < lim; jj += 8) {
        int s[8];
#pragma unroll
        for (int k = 0; k < 8; ++k) s[k] = __shfl(idx, (qt << 4) + jj + k);
        unsigned u[8];
#pragma unroll
        for (int k = 0; k < 8; ++k) {
          unsigned v = 0u;
          if (base + jj + k < cntq) v = *(const unsigned*)(Yp + (size_t)s[k] * 32 + li * 2);
          u[k] = v;
        }
#pragma unroll
        for (int k = 0; k < 8; ++k) {
          a0 += bits_to_f(u[k] << 16);
          a1 += bits_to_f(u[k] & 0xffff0000u);
        }
      }
    }
    if (live) {
      float2 o;
      o.x = zx + sc * a0 + bsum[c0];
      o.y = zy + sc * a1 + bsum[c0 + 1];
      *(float2*)(out + (size_t)node * 64 + c0) = o;
    }
  }
}

// ---------------- launch ----------------
extern "C" void kernel_launch(void* const* d_in, const int* in_sizes, int n_in,
                              void* d_out, int out_size, void* d_ws, size_t ws_size,
                              hipStream_t stream) {
  const float* x = (const float*)d_in[0];
  const int* ei = (const int*)d_in[1];
  const int N = in_sizes[0] / 128;
  const int E = in_sizes[3];
  const int* src = ei;
  const int* dst = ei + E;
  const float* Wl[3] = {(const float*)d_in[4], (const float*)d_in[9], (const float*)d_in[14]};
  const float* bl[3] = {(const float*)d_in[5], (const float*)d_in[10], (const float*)d_in[15]};
  const float* Wr[3] = {(const float*)d_in[6], (const float*)d_in[11], (const float*)d_in[16]};
  const float* Ws[3] = {(const float*)d_in[7], (const float*)d_in[12], (const float*)d_in[17]};
  const float* bs[3] = {(const float*)d_in[8], (const float*)d_in[13], (const float*)d_in[18]};

  const int NB = (N + 255) >> 8;
  const int NP1 = (E + P1_CHUNK - 1) / P1_CHUNK;

  size_t off = 0;
  auto carve = [&](size_t bytes) -> char* {
    char* p = (char*)d_ws + off;
    off += (bytes + 255) & ~(size_t)255;
    return p;
  };
  int* row_start = (int*)carve((size_t)N * 4);
  int* deg_arr = (int*)carve((size_t)N * 4);
  int* bcnt = (int*)carve((size_t)NB * 4);
  int* gcounter = (int*)carve(256);
  float* scale = (float*)carve((size_t)N * 4);
  int* srcs = (int*)carve((size_t)E * 4);
  int2* pairs = (int2*)carve((size_t)NB * BCAP * 8);
  ushort* Yb0 = (ushort*)carve((size_t)N * 128 * 2);
  float* Zf0 = (float*)carve((size_t)N * 128 * 4);
  ushort* Yb1 = (ushort*)carve((size_t)N * 128 * 2);
  float* Zf1 = (float*)carve((size_t)N * 128 * 4);
  ushort* Bh[3];
  ushort* Bo[3];
  float* bsum[3];
  for (int i = 0; i < 3; ++i) {
    Bh[i] = (ushort*)carve(128 * 256 * 2);
    Bo[i] = (ushort*)carve(128 * 256 * 2);
    bsum[i] = (float*)carve(128 * 4);
  }
  (void)ws_size;
  (void)n_in;
  (void)out_size;

  // K0: zero bucket counters + global counter (bcnt..gcounter are adjacent carves)
  size_t bcnt_pad = ((size_t)NB * 4 + 255) & ~(size_t)255;
  hipMemsetAsync(bcnt, 0, bcnt_pad + 4, stream);

  // K1: wpack || p1 (independent; both only need zeroed counters)
  fused_wpack_p1<<<NP1 + 384, 256, 0, stream>>>(
      src, dst, bcnt, pairs, E, NP1, Wl[0], Wr[0], Ws[0], bl[0], bs[0], Wl[1], Wr[1], Ws[1], bl[1],
      bs[1], Wl[2], Wr[2], Ws[2], bl[2], bs[2], Bh[0], Bo[0], bsum[0], Bh[1], Bo[1], bsum[1], Bh[2],
      Bo[2], bsum[2]);

  int g32 = (N + 31) / 32;   // 32-row blocks (M=256 GEMM)
  int g64 = (N + 63) / 64;   // 64-row blocks (M=128 GEMM)
  int gAgg = (N + 15) / 16;  // 16 nodes/block (agg64)

  // K2: p234 || gemm0 (independent: CSR place vs layer-0 GEMM) -> Yb0 (panels), Zf0
  fused_p234_gemm0<<<NB + g32, 256, 0, stream>>>(pairs, bcnt, gcounter, row_start, deg_arr, scale,
                                                 srcs, N, x, Bh[0], Bo[0], Yb0, Zf0, NB);
  // K3: agg(layer0) + gemm1 fused -> Yb1 (panels), Zf1
  fused_agg_gemm<256><<<g32, 256, 0, stream>>>(Yb0, Zf0, row_start, deg_arr, srcs, scale, bsum[0],
                                               Bh[1], Bo[1], Yb1, Zf1, N);
  // K4: agg(layer1) + gemm2 fused -> Yb0 (2 panels), Zf0
  fused_agg_gemm<128><<<g64, 256, 0, stream>>>(Yb1, Zf1, row_start, deg_arr, srcs, scale, bsum[1],
                                               Bh[2], Bo[2], Yb0, Zf0, N);
  // K5: final agg (no relu) -> out
  agg64_kernel<<<gAgg, 256, 0, stream>>>(Yb0, Zf0, row_start, deg_arr, srcs, scale, bsum[2],
                                         (float*)d_out, N);
}

// Round 10
// 273.736 us; speedup vs baseline: 1.2836x; 1.2836x over previous
//
#include <hip/hip_runtime.h>
#include <hip/hip_bf16.h>

// GNNEncoder: 3-layer GraphSAGE (mean agg), N=50000, E=800000.
// h' = act( mean_agg(x@Wl) + x@(Wr+Ws) + (bl+bs) )   (matmul-first by linearity)
// R19 = R18 compile fix: __builtin_nontemporal_load needs clang ext_vector
// pointers (f32x4), not HIP float4 class type. Theory unchanged: R16 best
// structure + nontemporal loads on read-once streams (srcs, Zprev/Z) so they
// don't evict hot Y lines from L2. Gather wall evidence: 4 structures all at
// 2.1-2.3 TB/s; depth- and occupancy-insensitive -> per-CU scattered-request
// ceiling.

#define LB __launch_bounds__

typedef __attribute__((ext_vector_type(8))) short short8;
typedef __attribute__((ext_vector_type(4))) float f32x4;

__device__ __forceinline__ unsigned short bf16_rne(float f) {
  unsigned u = __builtin_bit_cast(unsigned, f);
  unsigned r = u + 0x7fffu + ((u >> 16) & 1u);
  return (unsigned short)(r >> 16);
}
__device__ __forceinline__ float bf16_to_f(unsigned short us) {
  return __builtin_bit_cast(float, (unsigned)us << 16);
}
__device__ __forceinline__ float bits_to_f(unsigned u) {
  return __builtin_bit_cast(float, u);
}

// async global->LDS, 16B per lane; lds ptr must be wave-uniform (HW adds lane*16)
__device__ __forceinline__ void async16(const void* g, void* l) {
  __builtin_amdgcn_global_load_lds((const __attribute__((address_space(1))) unsigned*)g,
                                   (__attribute__((address_space(3))) unsigned*)l, 16, 0, 0);
}

// ---------------- CSR build: bucketed 2-pass sort ----------------
#define BCAP 8192
#define P1_CHUNK 4096

__device__ __forceinline__ void p1_body(int bid, const int* __restrict__ src,
                                        const int* __restrict__ dst, int* __restrict__ bcnt,
                                        int2* __restrict__ pairs, int E) {
  __shared__ int cnt[256];
  __shared__ int base[256];
  const int tid = threadIdx.x;
  cnt[tid] = 0;
  __syncthreads();
  const int e0 = bid * P1_CHUNK;
  int myb[16], myr[16], mys[16], myd[16];
#pragma unroll
  for (int i = 0; i < 16; ++i) {
    int e = e0 + i * 256 + tid;
    myb[i] = -1;
    if (e < E) {
      int s = src[e], d = dst[e];
      int b = d >> 8;
      myb[i] = b;
      mys[i] = s;
      myd[i] = d;
      myr[i] = atomicAdd(&cnt[b], 1);
    }
  }
  __syncthreads();
  base[tid] = (cnt[tid] > 0) ? atomicAdd(&bcnt[tid], cnt[tid]) : 0;
  __syncthreads();
#pragma unroll
  for (int i = 0; i < 16; ++i) {
    int b = myb[i];
    if (b >= 0) {
      int p = base[b] + myr[i];
      if (p < BCAP) pairs[(size_t)b * BCAP + p] = make_int2(mys[i], myd[i]);
    }
  }
}

// Fused: per-bucket hist + local scan + ONE atomicAdd region-claim + place.
__device__ __forceinline__ void p234_body(int b, const int2* __restrict__ pairs,
                                          const int* __restrict__ bcnt, int* __restrict__ gcounter,
                                          int* __restrict__ row_start, int* __restrict__ deg_arr,
                                          float* __restrict__ scale, int* __restrict__ srcs, int N) {
  __shared__ int h[256];
  __shared__ int sc[256];
  __shared__ int cur[256];
  __shared__ int shared_bb;
  const int tid = threadIdx.x;
  h[tid] = 0;
  __syncthreads();
  int m = bcnt[b];
  if (m > BCAP) m = BCAP;
  for (int i = tid; i < m; i += 256) {
    atomicAdd(&h[pairs[(size_t)b * BCAP + i].y & 255], 1);
  }
  __syncthreads();
  const int deg = h[tid];
  sc[tid] = deg;
  __syncthreads();
  for (int off = 1; off < 256; off <<= 1) {
    int add = (tid >= off) ? sc[tid - off] : 0;
    __syncthreads();
    sc[tid] += add;
    __syncthreads();
  }
  if (tid == 0) shared_bb = atomicAdd(gcounter, sc[255]);
  __syncthreads();
  const int abs_off = shared_bb + sc[tid] - deg;
  const int node = b * 256 + tid;
  if (node < N) {
    row_start[node] = abs_off;
    deg_arr[node] = deg;
    scale[node] = 1.0f / (float)(deg > 1 ? deg : 1);
  }
  cur[tid] = abs_off;
  __syncthreads();
  for (int i = tid; i < m; i += 256) {
    int2 pr = pairs[(size_t)b * BCAP + i];
    int p = atomicAdd(&cur[pr.y & 255], 1);
    srcs[p] = pr.x;
  }
}

// ---------------- weights -> fragment-ordered hi/lo bf16 + bias ----------------
__device__ __forceinline__ void wpack_body(int wb, const float* __restrict__ Wl0,
                                           const float* __restrict__ Wr0,
                                           const float* __restrict__ Ws0,
                                           const float* __restrict__ bl0,
                                           const float* __restrict__ bs0,
                                           const float* __restrict__ Wl1,
                                           const float* __restrict__ Wr1,
                                           const float* __restrict__ Ws1,
                                           const float* __restrict__ bl1,
                                           const float* __restrict__ bs1,
                                           const float* __restrict__ Wl2,
                                           const float* __restrict__ Wr2,
                                           const float* __restrict__ Ws2,
                                           const float* __restrict__ bl2,
                                           const float* __restrict__ bs2, ushort* __restrict__ Bh0,
                                           ushort* __restrict__ Bo0, float* __restrict__ bb0,
                                           ushort* __restrict__ Bh1, ushort* __restrict__ Bo1,
                                           float* __restrict__ bb1, ushort* __restrict__ Bh2,
                                           ushort* __restrict__ Bo2, float* __restrict__ bb2) {
  const int layer = wb >> 7;
  const int xb = wb & 127;
  const float *Wl, *Wr, *Ws, *bl, *bs;
  ushort *Bh, *Bo;
  float* bb;
  int M;
  if (layer == 0) {
    Wl = Wl0; Wr = Wr0; Ws = Ws0; bl = bl0; bs = bs0; Bh = Bh0; Bo = Bo0; bb = bb0; M = 256;
  } else if (layer == 1) {
    Wl = Wl1; Wr = Wr1; Ws = Ws1; bl = bl1; bs = bs1; Bh = Bh1; Bo = Bo1; bb = bb1; M = 256;
  } else {
    Wl = Wl2; Wr = Wr2; Ws = Ws2; bl = bl2; bs = bs2; Bh = Bh2; Bo = Bo2; bb = bb2; M = 128;
  }
  const int DO = M / 2;
  int idx = xb * 256 + (int)threadIdx.x;
  if (idx < 128 * M) {
    int k = idx / M, c = idx - k * M;
    float v = (c < DO) ? Wl[k * DO + c] : (Wr[k * DO + (c - DO)] + Ws[k * DO + (c - DO)]);
    unsigned short h = bf16_rne(v);
    unsigned short l = bf16_rne(v - bf16_to_f(h));
    int d = ((k >> 3) * M + c) * 8 + (k & 7);
    Bh[d] = h;
    Bo[d] = l;
  }
  if (idx < DO) bb[idx] = bl[idx] + bs[idx];
}

// ---------------- MFMA GEMM (A = fp32 in LDS, swizzled 16B granules) ----------------
__device__ __forceinline__ void split8v(f32x4 f0, f32x4 f1, short8& h, short8& l) {
  float f[8] = {f0[0], f0[1], f0[2], f0[3], f1[0], f1[1], f1[2], f1[3]};
#pragma unroll
  for (int j = 0; j < 8; ++j) {
    unsigned u = __builtin_bit_cast(unsigned, f[j]);
    h[j] = (short)(u >> 16);
    l[j] = (short)bf16_rne(f[j] - bits_to_f(u & 0xffff0000u));
  }
}

// LDS layout: row r (BROWS rows) x 512B; granule g of row holds global granule
// g ^ (r&15). Wave tile 32x64 (acc 2x4).
template <int M>
__device__ __forceinline__ void gemm_compute(int bx, const char* smem,
                                             const ushort* __restrict__ Bhi,
                                             const ushort* __restrict__ Blo,
                                             ushort* __restrict__ Yb, float* __restrict__ Z,
                                             int n) {
  constexpr int DO = M / 2;
  constexpr int NWC = (M >= 256) ? 4 : 2;
  constexpr int NWR = 4 / NWC;
  constexpr int BROWS = 32 * NWR;
  const int tid = threadIdx.x;
  const int w = tid >> 6, l = tid & 63;
  const int q = l >> 4, m16 = l & 15;
  const int rowBase = bx * BROWS + (w / NWC) * 32;
  const int colBase = (w % NWC) * 64;

  f32x4 acc[2][4] = {};
  const int rl0 = (w / NWC) * 32 + m16;

#pragma unroll
  for (int s = 0; s < 4; ++s) {
    short8 ah[2], al[2], bh[4], bo[4];
    const int kb = s * 4 + q;
#pragma unroll
    for (int i = 0; i < 2; ++i) {
      int rl = rl0 + i * 16;  // rl & 15 == m16
      int g0 = (2 * kb) ^ m16;
      int g1 = (2 * kb + 1) ^ m16;
      f32x4 fa = *(const f32x4*)(smem + (size_t)rl * 512 + g0 * 16);
      f32x4 fb = *(const f32x4*)(smem + (size_t)rl * 512 + g1 * 16);
      split8v(fa, fb, ah[i], al[i]);
    }
#pragma unroll
    for (int j = 0; j < 4; ++j) {
      size_t off = ((size_t)kb * M + colBase + j * 16 + m16) * 8;
      bh[j] = *(const short8*)(Bhi + off);
      bo[j] = *(const short8*)(Blo + off);
    }
#pragma unroll
    for (int i = 0; i < 2; ++i)
#pragma unroll
      for (int j = 0; j < 4; ++j) {
        acc[i][j] = __builtin_amdgcn_mfma_f32_16x16x32_bf16(ah[i], bh[j], acc[i][j], 0, 0, 0);
        acc[i][j] = __builtin_amdgcn_mfma_f32_16x16x32_bf16(ah[i], bo[j], acc[i][j], 0, 0, 0);
        acc[i][j] = __builtin_amdgcn_mfma_f32_16x16x32_bf16(al[i], bh[j], acc[i][j], 0, 0, 0);
      }
  }

#pragma unroll
  for (int i = 0; i < 2; ++i) {
    int rb = rowBase + i * 16 + q * 4;
#pragma unroll
    for (int j = 0; j < 4; ++j) {
      int c = colBase + j * 16 + m16;
#pragma unroll
      for (int r = 0; r < 4; ++r) {
        int row = rb + r;
        if (row < n) {
          float v = acc[i][j][r];
          if (c < DO)
            Yb[(size_t)row * DO + c] = bf16_rne(v);
          else
            Z[(size_t)row * DO + (c - DO)] = v;
        }
      }
    }
  }
}

// layer-0 GEMM: stage x (fp32) global->LDS with inverse-swizzled source, then compute
__device__ __forceinline__ void gemm0_body(int bx, const float* __restrict__ x,
                                           const ushort* __restrict__ Bh,
                                           const ushort* __restrict__ Bo, ushort* __restrict__ Yb,
                                           float* __restrict__ Z, int n, char* smem) {
  const int tid = threadIdx.x;
  const int wbase = tid & ~63;
#pragma unroll
  for (int r = 0; r < 4; ++r) {  // 32 rows x 512B
    int ell = r * 256 + tid;
    int row = ell >> 5, gl = ell & 31;
    int grow = bx * 32 + row;
    if (grow >= n) grow = n - 1;
    int gs = gl ^ (row & 15);
    async16(x + (size_t)grow * 128 + gs * 4, smem + (size_t)(r * 256 + wbase) * 16);
  }
  __syncthreads();
  gemm_compute<256>(bx, smem, Bh, Bo, Yb, Z, n);
}

// ---------------- fused agg + next-layer GEMM ----------------
// Quarter-per-node gather: wave handles 4 nodes (one per 16-lane quarter).
// All 16 lanes of a quarter read the SAME source row (lane = 16B granule) ->
// lane-local column accumulation, NO cross-lane reduce, full-wave epilogue.
// Loads issue 8-deep, predicated per quarter (wave-uniform trip count = max
// deg over the 4 quarters). srcs/Zprev are nontemporal (read-once streams;
// keep them out of L2 so Y lines stay hot). Y gathers use normal caching.
__device__ __forceinline__ void acc8(float* a, uint4 u) {
  a[0] += bits_to_f(u.x << 16);
  a[1] += bits_to_f(u.x & 0xffff0000u);
  a[2] += bits_to_f(u.y << 16);
  a[3] += bits_to_f(u.y & 0xffff0000u);
  a[4] += bits_to_f(u.z << 16);
  a[5] += bits_to_f(u.z & 0xffff0000u);
  a[6] += bits_to_f(u.w << 16);
  a[7] += bits_to_f(u.w & 0xffff0000u);
}

template <int M>
__global__ LB(256, 4) void fused_agg_gemm(const ushort* __restrict__ Y,
                                          const float* __restrict__ Zprev,
                                          const int* __restrict__ row_start,
                                          const int* __restrict__ deg_arr,
                                          const int* __restrict__ srcs,
                                          const float* __restrict__ scale,
                                          const float* __restrict__ bsum,
                                          const ushort* __restrict__ Bhi,
                                          const ushort* __restrict__ Blo, ushort* __restrict__ Yb,
                                          float* __restrict__ Zf, int n) {
  constexpr int BROWS = (M >= 256) ? 32 : 64;
  __shared__ __align__(16) char smem[BROWS * 512];
  const int tid = threadIdx.x;
  const int w = tid >> 6;
  const int lane = tid & 63;
  const int qt = lane >> 4;  // quarter -> node within wave's group of 4
  const int li = lane & 15;  // 16B granule within 256B row
  const int blockRow0 = blockIdx.x * BROWS;
  const uint4* Y4 = (const uint4*)Y;

#pragma unroll 1
  for (int t = 0; t < BROWS / 16; ++t) {
    const int r = t * 16 + w * 4 + qt;  // A-tile row owned by this quarter
    const int node = blockRow0 + r;
    const bool live = node < n;  // quarter-uniform
    const int cn = live ? node : n - 1;
    const int e0q = row_start[cn];
    const int cntq = live ? deg_arr[cn] : 0;
    const float sc = scale[cn];
    const f32x4* Zp = (const f32x4*)Zprev;
    f32x4 z0 = __builtin_nontemporal_load(Zp + (size_t)cn * 32 + 2 * li);
    f32x4 z1 = __builtin_nontemporal_load(Zp + (size_t)cn * 32 + 2 * li + 1);
    float4 b0 = ((const float4*)bsum)[2 * li];
    float4 b1 = ((const float4*)bsum)[2 * li + 1];
    float a[8] = {0.f, 0.f, 0.f, 0.f, 0.f, 0.f, 0.f, 0.f};

    int cm = cntq;  // wave-uniform trip count = max over quarters
    cm = max(cm, __shfl_xor(cm, 16));
    cm = max(cm, __shfl_xor(cm, 32));

    for (int base = 0; base < cm; base += 16) {
      int idx = (base + li < cntq) ? __builtin_nontemporal_load(srcs + e0q + base + li) : 0;
      int lim = cm - base;
      if (lim > 16) lim = 16;
      for (int jj = 0; jj < lim; jj += 8) {  // 8 loads in flight / quarter-row
        int s[8];
#pragma unroll
        for (int k = 0; k < 8; ++k) s[k] = __shfl(idx, (qt << 4) + jj + k);
        uint4 u[8];
#pragma unroll
        for (int k = 0; k < 8; ++k) {
          uint4 v = make_uint4(0u, 0u, 0u, 0u);
          if (base + jj + k < cntq) v = Y4[(size_t)s[k] * 16 + li];
          u[k] = v;
        }
#pragma unroll
        for (int k = 0; k < 8; ++k) acc8(a, u[k]);
      }
    }
    // lane-local epilogue (no reduction): cols 8li..8li+7 of node
    float4 o0, o1;
    o0.x = fmaxf(z0[0] + sc * a[0] + b0.x, 0.f);
    o0.y = fmaxf(z0[1] + sc * a[1] + b0.y, 0.f);
    o0.z = fmaxf(z0[2] + sc * a[2] + b0.z, 0.f);
    o0.w = fmaxf(z0[3] + sc * a[3] + b0.w, 0.f);
    o1.x = fmaxf(z1[0] + sc * a[4] + b1.x, 0.f);
    o1.y = fmaxf(z1[1] + sc * a[5] + b1.y, 0.f);
    o1.z = fmaxf(z1[2] + sc * a[6] + b1.z, 0.f);
    o1.w = fmaxf(z1[3] + sc * a[7] + b1.w, 0.f);
    *(float4*)(smem + (size_t)r * 512 + (size_t)(((2 * li) ^ (r & 15)) * 16)) = o0;
    *(float4*)(smem + (size_t)r * 512 + (size_t)(((2 * li + 1) ^ (r & 15)) * 16)) = o1;
  }
  __syncthreads();
  gemm_compute<M>(blockIdx.x, smem, Bhi, Blo, Yb, Zf, n);
}

// ---------------- fused launch-overlap kernels ----------------
__global__ LB(256) void fused_wpack_p1(const int* __restrict__ src, const int* __restrict__ dst,
                                       int* __restrict__ bcnt, int2* __restrict__ pairs, int E,
                                       int NP1, const float* Wl0, const float* Wr0, const float* Ws0,
                                       const float* bl0, const float* bs0, const float* Wl1,
                                       const float* Wr1, const float* Ws1, const float* bl1,
                                       const float* bs1, const float* Wl2, const float* Wr2,
                                       const float* Ws2, const float* bl2, const float* bs2,
                                       ushort* Bh0, ushort* Bo0, float* bb0, ushort* Bh1,
                                       ushort* Bo1, float* bb1, ushort* Bh2, ushort* Bo2,
                                       float* bb2) {
  if ((int)blockIdx.x < NP1) {
    p1_body(blockIdx.x, src, dst, bcnt, pairs, E);
  } else {
    wpack_body(blockIdx.x - NP1, Wl0, Wr0, Ws0, bl0, bs0, Wl1, Wr1, Ws1, bl1, bs1, Wl2, Wr2, Ws2,
               bl2, bs2, Bh0, Bo0, bb0, Bh1, Bo1, bb1, Bh2, Bo2, bb2);
  }
}

__global__ LB(256, 5) void fused_p234_gemm0(const int2* __restrict__ pairs,
                                            const int* __restrict__ bcnt, int* __restrict__ gcounter,
                                            int* __restrict__ row_start, int* __restrict__ deg_arr,
                                            float* __restrict__ scale, int* __restrict__ srcs, int N,
                                            const float* __restrict__ x,
                                            const ushort* __restrict__ Bh0,
                                            const ushort* __restrict__ Bo0, ushort* __restrict__ Yb,
                                            float* __restrict__ Zf, int NB) {
  __shared__ __align__(16) char smem[32 * 512];
  if ((int)blockIdx.x < NB) {
    p234_body(blockIdx.x, pairs, bcnt, gcounter, row_start, deg_arr, scale, srcs, N);
  } else {
    gemm0_body(blockIdx.x - NB, x, Bh0, Bo0, Yb, Zf, N, smem);
  }
}

// ---------------- final aggregation (DO=64) ----------------
// Quarter-per-node, 16 nodes/block, 8-deep predicated uint2 gather.
__global__ LB(256, 4) void agg64_kernel(const ushort* __restrict__ Y, const float* __restrict__ Z,
                                        const int* __restrict__ row_start,
                                        const int* __restrict__ deg_arr, const int* __restrict__ srcs,
                                        const float* __restrict__ scale,
                                        const float* __restrict__ bsum, float* __restrict__ out,
                                        int n) {
  const int tid = threadIdx.x;
  const int lane = tid & 63;
  const int qt = lane >> 4;
  const int li = lane & 15;  // 8B granule within 128B row
  const int node = blockIdx.x * 16 + (tid >> 6) * 4 + qt;
  const bool live = node < n;  // quarter-uniform
  const int cn = live ? node : n - 1;
  const int e0q = row_start[cn];
  const int cntq = live ? deg_arr[cn] : 0;
  const uint2* Yu = (const uint2*)Y;  // row = 16 uint2
  float a0 = 0.f, a1 = 0.f, a2 = 0.f, a3 = 0.f;
  const float sc = scale[cn];
  f32x4 z = __builtin_nontemporal_load((const f32x4*)Z + (size_t)cn * 16 + li);
  float4 b = ((const float4*)bsum)[li];

  int cm = cntq;
  cm = max(cm, __shfl_xor(cm, 16));
  cm = max(cm, __shfl_xor(cm, 32));

  for (int base = 0; base < cm; base += 16) {
    int idx = (base + li < cntq) ? __builtin_nontemporal_load(srcs + e0q + base + li) : 0;
    int lim = cm - base;
    if (lim > 16) lim = 16;
    for (int jj = 0; jj < lim; jj += 8) {
      int s[8];
#pragma unroll
      for (int k = 0; k < 8; ++k) s[k] = __shfl(idx, (qt << 4) + jj + k);
      uint2 u[8];
#pragma unroll
      for (int k = 0; k < 8; ++k) {
        uint2 v = make_uint2(0u, 0u);
        if (base + jj + k < cntq) v = Yu[(size_t)s[k] * 16 + li];
        u[k] = v;
      }
#pragma unroll
      for (int k = 0; k < 8; ++k) {
        a0 += bits_to_f(u[k].x << 16);
        a1 += bits_to_f(u[k].x & 0xffff0000u);
        a2 += bits_to_f(u[k].y << 16);
        a3 += bits_to_f(u[k].y & 0xffff0000u);
      }
    }
  }
  if (live) {
    float4 o;
    o.x = z[0] + sc * a0 + b.x;
    o.y = z[1] + sc * a1 + b.y;
    o.z = z[2] + sc * a2 + b.z;
    o.w = z[3] + sc * a3 + b.w;
    ((float4*)out)[(size_t)node * 16 + li] = o;
  }
}

// ---------------- launch ----------------
extern "C" void kernel_launch(void* const* d_in, const int* in_sizes, int n_in,
                              void* d_out, int out_size, void* d_ws, size_t ws_size,
                              hipStream_t stream) {
  const float* x = (const float*)d_in[0];
  const int* ei = (const int*)d_in[1];
  const int N = in_sizes[0] / 128;
  const int E = in_sizes[3];
  const int* src = ei;
  const int* dst = ei + E;
  const float* Wl[3] = {(const float*)d_in[4], (const float*)d_in[9], (const float*)d_in[14]};
  const float* bl[3] = {(const float*)d_in[5], (const float*)d_in[10], (const float*)d_in[15]};
  const float* Wr[3] = {(const float*)d_in[6], (const float*)d_in[11], (const float*)d_in[16]};
  const float* Ws[3] = {(const float*)d_in[7], (const float*)d_in[12], (const float*)d_in[17]};
  const float* bs[3] = {(const float*)d_in[8], (const float*)d_in[13], (const float*)d_in[18]};

  const int NB = (N + 255) >> 8;
  const int NP1 = (E + P1_CHUNK - 1) / P1_CHUNK;

  size_t off = 0;
  auto carve = [&](size_t bytes) -> char* {
    char* p = (char*)d_ws + off;
    off += (bytes + 255) & ~(size_t)255;
    return p;
  };
  int* row_start = (int*)carve((size_t)N * 4);
  int* deg_arr = (int*)carve((size_t)N * 4);
  int* bcnt = (int*)carve((size_t)NB * 4);
  int* gcounter = (int*)carve(256);
  float* scale = (float*)carve((size_t)N * 4);
  int* srcs = (int*)carve((size_t)E * 4);
  int2* pairs = (int2*)carve((size_t)NB * BCAP * 8);
  ushort* Yb0 = (ushort*)carve((size_t)N * 128 * 2);
  float* Zf0 = (float*)carve((size_t)N * 128 * 4);
  ushort* Yb1 = (ushort*)carve((size_t)N * 128 * 2);
  float* Zf1 = (float*)carve((size_t)N * 128 * 4);
  ushort* Bh[3];
  ushort* Bo[3];
  float* bsum[3];
  for (int i = 0; i < 3; ++i) {
    Bh[i] = (ushort*)carve(128 * 256 * 2);
    Bo[i] = (ushort*)carve(128 * 256 * 2);
    bsum[i] = (float*)carve(128 * 4);
  }
  (void)ws_size;
  (void)n_in;
  (void)out_size;

  // K0: zero bucket counters + global counter (bcnt..gcounter are adjacent carves)
  size_t bcnt_pad = ((size_t)NB * 4 + 255) & ~(size_t)255;
  hipMemsetAsync(bcnt, 0, bcnt_pad + 4, stream);

  // K1: wpack || p1 (independent; both only need zeroed counters)
  fused_wpack_p1<<<NP1 + 384, 256, 0, stream>>>(
      src, dst, bcnt, pairs, E, NP1, Wl[0], Wr[0], Ws[0], bl[0], bs[0], Wl[1], Wr[1], Ws[1], bl[1],
      bs[1], Wl[2], Wr[2], Ws[2], bl[2], bs[2], Bh[0], Bo[0], bsum[0], Bh[1], Bo[1], bsum[1], Bh[2],
      Bo[2], bsum[2]);

  int g32 = (N + 31) / 32;   // 32-row blocks (M=256 GEMM)
  int g64 = (N + 63) / 64;   // 64-row blocks (M=128 GEMM)
  int gAgg = (N + 15) / 16;  // 16 nodes/block (agg64)

  // K2: p234 || gemm0 (independent: CSR place vs layer-0 GEMM) -> Yb0, Zf0
  fused_p234_gemm0<<<NB + g32, 256, 0, stream>>>(pairs, bcnt, gcounter, row_start, deg_arr, scale,
                                                 srcs, N, x, Bh[0], Bo[0], Yb0, Zf0, NB);
  // K3: agg(layer0) + gemm1 fused -> Yb1, Zf1
  fused_agg_gemm<256><<<g32, 256, 0, stream>>>(Yb0, Zf0, row_start, deg_arr, srcs, scale, bsum[0],
                                               Bh[1], Bo[1], Yb1, Zf1, N);
  // K4: agg(layer1) + gemm2 fused -> Yb0, Zf0 (ping-pong back; safe: different buffers)
  fused_agg_gemm<128><<<g64, 256, 0, stream>>>(Yb1, Zf1, row_start, deg_arr, srcs, scale, bsum[1],
                                               Bh[2], Bo[2], Yb0, Zf0, N);
  // K5: final agg (no relu) -> out
  agg64_kernel<<<gAgg, 256, 0, stream>>>(Yb0, Zf0, row_start, deg_arr, srcs, scale, bsum[2],
                                         (float*)d_out, N);
}